// Round 1
// baseline (1123.546 us; speedup 1.0000x reference)
//
#include <hip/hip_runtime.h>
#include <cstdint>
#include <cstddef>

#define K_NN   1000
#define NS     2000   // N_SAMPLE
#define MPTS   5000   // M
#define CDIM   128
#define KSP    50
#define EPSF   1e-8f

// float -> order-preserving uint key (all totals ordered like float compare)
__device__ __forceinline__ unsigned int f2key(float x) {
    unsigned int u = __float_as_uint(x);
    return (u & 0x80000000u) ? ~u : (u | 0x80000000u);
}
__device__ __forceinline__ float key2f(unsigned int k) {
    unsigned int b = (k & 0x80000000u) ? (k & 0x7fffffffu) : ~k;
    return __uint_as_float(b);
}

// ---------------- K0: squared norms ----------------
// bb[brb][m] = ||feat[b][m]||^2   (brb = branch*2 + b, 4*5000)
// aa[brb][n] = ||feat[b][rand_idx[n]]||^2  (4*2000)
__global__ void norms_kernel(const float* __restrict__ feat1,
                             const float* __restrict__ feat2,
                             const int* __restrict__ ridx1,
                             const int* __restrict__ ridx2,
                             float* __restrict__ bb,
                             float* __restrict__ aa)
{
    int gid = blockIdx.x * blockDim.x + threadIdx.x;
    const int total_bb = 4 * MPTS;
    const int total_aa = 4 * NS;
    if (gid < total_bb) {
        int brb = gid / MPTS;
        int m   = gid % MPTS;
        const float* feat = (brb < 2) ? feat1 : feat2;
        int b = brb & 1;
        const float* row = feat + ((size_t)b * MPTS + m) * CDIM;
        float s = 0.f;
        #pragma unroll
        for (int c = 0; c < CDIM; c += 4) {
            float4 v = *reinterpret_cast<const float4*>(row + c);
            s += v.x*v.x + v.y*v.y + v.z*v.z + v.w*v.w;
        }
        bb[gid] = s;
    } else if (gid < total_bb + total_aa) {
        int t   = gid - total_bb;
        int brb = t / NS;
        int n   = t % NS;
        const float* feat = (brb < 2) ? feat1 : feat2;
        const int*  ridx  = (brb < 2) ? ridx1 : ridx2;
        int b = brb & 1;
        int m = ridx[n];
        const float* row = feat + ((size_t)b * MPTS + m) * CDIM;
        float s = 0.f;
        #pragma unroll
        for (int c = 0; c < CDIM; c += 4) {
            float4 v = *reinterpret_cast<const float4*>(row + c);
            s += v.x*v.x + v.y*v.y + v.z*v.z + v.w*v.w;
        }
        aa[t] = s;
    }
}

// ---------------- K1: d2 GEMM ----------------
// d2[r][m] = aa[row0+r] + bb[m] - 2 * dot(feat[ridx[row0+r]], feat[m])
#define BM 128
#define BN 128
#define BK 32
__global__ __launch_bounds__(256)
void d2_gemm_kernel(const float* __restrict__ feat_b,   // [MPTS][CDIM] for this batch
                    const int*   __restrict__ ridx,
                    const float* __restrict__ aa_bb,    // [NS]
                    const float* __restrict__ bb_bb,    // [MPTS]
                    float*       __restrict__ d2,       // [rows][MPTS]
                    int row0, int rows)
{
    __shared__ float As[BK][BM + 4];
    __shared__ float Bs[BK][BN + 4];

    const int tid = threadIdx.x;
    const int tx  = tid & 15;    // N direction
    const int ty  = tid >> 4;    // M (row) direction
    const int m0  = blockIdx.x * BN;
    const int r0  = blockIdx.y * BM;

    float acc[2][4][2][4];
    #pragma unroll
    for (int a = 0; a < 2; ++a)
      #pragma unroll
      for (int b = 0; b < 4; ++b)
        #pragma unroll
        for (int c = 0; c < 2; ++c)
          #pragma unroll
          for (int d = 0; d < 4; ++d) acc[a][b][c][d] = 0.f;

    // precompute gather sources for the 4 staged rows this thread loads
    int asrc[4]; int bsrc[4];
    const int lr = tid >> 3;           // 0..31
    const int lc = (tid & 7) << 2;     // 0,4,...,28
    #pragma unroll
    for (int p = 0; p < 4; ++p) {
        int r  = (p << 5) + lr;        // 0..127
        int rr = r0 + r;
        int n  = row0 + rr;
        asrc[p] = (rr < rows && n < NS) ? ridx[n] : 0;
        int m  = m0 + r;
        bsrc[p] = (m < MPTS) ? m : 0;
    }

    for (int k0 = 0; k0 < CDIM; k0 += BK) {
        #pragma unroll
        for (int p = 0; p < 4; ++p) {
            int r = (p << 5) + lr;
            float4 v = *reinterpret_cast<const float4*>(feat_b + (size_t)asrc[p] * CDIM + k0 + lc);
            As[lc + 0][r] = v.x; As[lc + 1][r] = v.y; As[lc + 2][r] = v.z; As[lc + 3][r] = v.w;
            float4 w = *reinterpret_cast<const float4*>(feat_b + (size_t)bsrc[p] * CDIM + k0 + lc);
            Bs[lc + 0][r] = w.x; Bs[lc + 1][r] = w.y; Bs[lc + 2][r] = w.z; Bs[lc + 3][r] = w.w;
        }
        __syncthreads();
        #pragma unroll 4
        for (int k = 0; k < BK; ++k) {
            float a[2][4], b[2][4];
            #pragma unroll
            for (int ib = 0; ib < 2; ++ib)
                *reinterpret_cast<float4*>(a[ib]) =
                    *reinterpret_cast<const float4*>(&As[k][ib * 64 + ty * 4]);
            #pragma unroll
            for (int jb = 0; jb < 2; ++jb)
                *reinterpret_cast<float4*>(b[jb]) =
                    *reinterpret_cast<const float4*>(&Bs[k][jb * 64 + tx * 4]);
            #pragma unroll
            for (int ib = 0; ib < 2; ++ib)
              #pragma unroll
              for (int ii = 0; ii < 4; ++ii)
                #pragma unroll
                for (int jb = 0; jb < 2; ++jb)
                  #pragma unroll
                  for (int jj = 0; jj < 4; ++jj)
                      acc[ib][ii][jb][jj] += a[ib][ii] * b[jb][jj];
        }
        __syncthreads();
    }

    // epilogue: d2 = aa + bb - 2*dot
    #pragma unroll
    for (int ib = 0; ib < 2; ++ib) {
        #pragma unroll
        for (int ii = 0; ii < 4; ++ii) {
            int r = r0 + ib * 64 + ty * 4 + ii;
            if (r >= rows) continue;
            int n = row0 + r;
            float an = aa_bb[n];
            #pragma unroll
            for (int jb = 0; jb < 2; ++jb) {
                int m = m0 + jb * 64 + tx * 4;
                if (m >= MPTS) continue;
                float4 bv = *reinterpret_cast<const float4*>(bb_bb + m);
                float4 o;
                o.x = an + bv.x - 2.f * acc[ib][ii][jb][0];
                o.y = an + bv.y - 2.f * acc[ib][ii][jb][1];
                o.z = an + bv.z - 2.f * acc[ib][ii][jb][2];
                o.w = an + bv.w - 2.f * acc[ib][ii][jb][3];
                *reinterpret_cast<float4*>(d2 + (size_t)r * MPTS + m) = o;
            }
        }
    }
}

// ---------------- K2: per-row radix-select + cosine reduction ----------------
__global__ __launch_bounds__(256)
void select_kernel(const float* __restrict__ d2,      // [rows][MPTS]
                   const float* __restrict__ dist_b,  // [MPTS][MPTS]
                   const int*   __restrict__ ridx,
                   float* __restrict__ sims_out,      // [rows]
                   int row0)
{
    __shared__ unsigned int keys[MPTS];
    __shared__ unsigned int hist[256];
    __shared__ unsigned int scanbuf[256];
    __shared__ unsigned int bc_prefix, bc_krem;
    __shared__ float wsum[3][4];

    const int tid = threadIdx.x;
    const int r   = blockIdx.x;
    const int n   = row0 + r;
    const float* row = d2 + (size_t)r * MPTS;

    // load + transform to orderable keys
    for (int i4 = tid; i4 < MPTS / 4; i4 += 256) {
        float4 v = reinterpret_cast<const float4*>(row)[i4];
        keys[i4 * 4 + 0] = f2key(v.x);
        keys[i4 * 4 + 1] = f2key(v.y);
        keys[i4 * 4 + 2] = f2key(v.z);
        keys[i4 * 4 + 3] = f2key(v.w);
    }
    __syncthreads();

    // MSB-first radix select: find key T of the K_NN-th smallest element
    unsigned int prefix = 0;
    int krem = K_NN;
    for (int pass = 0; pass < 4; ++pass) {
        int shift = 24 - 8 * pass;
        hist[tid] = 0;
        __syncthreads();
        for (int i = tid; i < MPTS; i += 256) {
            unsigned int k = keys[i];
            if (pass == 0 || ((k >> (shift + 8)) == prefix))
                atomicAdd(&hist[(k >> shift) & 255u], 1u);
        }
        __syncthreads();
        if (tid == 0) {
            unsigned int cum = 0; int bsel = 0;
            for (; bsel < 256; ++bsel) {
                unsigned int h = hist[bsel];
                if (cum + h >= (unsigned int)krem) break;
                cum += h;
            }
            bc_prefix = (prefix << 8) | (unsigned int)bsel;
            bc_krem   = (unsigned int)(krem - (int)cum);
        }
        __syncthreads();
        prefix = bc_prefix;
        krem   = (int)bc_krem;
        __syncthreads();
    }
    const unsigned int T = prefix;
    const int need_eq = krem;   // how many ==T to take, in index order (matches top_k ties)

    // stable selection: chunked so index order is preserved
    const int CH = (MPTS + 255) / 256;   // 20
    int start = tid * CH; if (start > MPTS) start = MPTS;
    int end = start + CH; if (end > MPTS) end = MPTS;

    int cnt_eq = 0;
    for (int i = start; i < end; ++i) cnt_eq += (keys[i] == T) ? 1 : 0;
    scanbuf[tid] = (unsigned int)cnt_eq;
    __syncthreads();
    for (int off = 1; off < 256; off <<= 1) {
        unsigned int v = (tid >= off) ? scanbuf[tid - off] : 0u;
        __syncthreads();
        scanbuf[tid] += v;
        __syncthreads();
    }
    int base_eq = (int)scanbuf[tid] - cnt_eq;  // exclusive prefix

    const int col = ridx[n];
    float num = 0.f, s1 = 0.f, s2 = 0.f;
    int local_eq = 0;
    for (int i = start; i < end; ++i) {
        unsigned int k = keys[i];
        bool sel;
        if (k < T) sel = true;
        else if (k == T) { sel = (base_eq + local_eq) < need_eq; ++local_eq; }
        else sel = false;
        if (sel) {
            float d2v = key2f(k);
            float dc  = fmaxf(d2v, 1e-12f);
            float val = __builtin_sqrtf(dc);
            float f   = dist_b[(size_t)i * MPTS + col];
            num += val * f;
            s1  += val * val;
            s2  += f * f;
        }
    }

    // block reduce (num, s1, s2)
    #pragma unroll
    for (int off = 32; off; off >>= 1) {
        num += __shfl_down(num, off, 64);
        s1  += __shfl_down(s1,  off, 64);
        s2  += __shfl_down(s2,  off, 64);
    }
    int wave = tid >> 6, lane = tid & 63;
    if (lane == 0) { wsum[0][wave] = num; wsum[1][wave] = s1; wsum[2][wave] = s2; }
    __syncthreads();
    if (tid == 0) {
        float N = wsum[0][0] + wsum[0][1] + wsum[0][2] + wsum[0][3];
        float A = wsum[1][0] + wsum[1][1] + wsum[1][2] + wsum[1][3];
        float B = wsum[2][0] + wsum[2][1] + wsum[2][2] + wsum[2][3];
        float den = fmaxf(__builtin_sqrtf(A), EPSF) * fmaxf(__builtin_sqrtf(B), EPSF);
        sims_out[r] = 1.f - fabsf(N / den);
    }
}

// ---------------- K3: small C-matrix losses ----------------
// jobs 0-3: frob(X X^T, I) for C12,C21,C12n,C21n -> acc[0]
// jobs 4,5: frob(C12@C21, I), frob(C21@C12, I)   -> acc[1]
// job  6  : sum (C12-C12n)^2 + (C21-C21n)^2      -> acc[2]
__global__ __launch_bounds__(256)
void closs_kernel(const float* __restrict__ C12,  const float* __restrict__ C21,
                  const float* __restrict__ C12n, const float* __restrict__ C21n,
                  float* __restrict__ acc)
{
    int job = blockIdx.x >> 1;
    int b   = blockIdx.x & 1;
    int tid = threadIdx.x;
    size_t boff = (size_t)b * KSP * KSP;
    __shared__ float X[KSP * KSP];
    __shared__ float Y[KSP * KSP];
    float local = 0.f;

    if (job == 6) {
        for (int i = tid; i < KSP * KSP; i += 256) {
            float dA = C12[boff + i] - C12n[boff + i];
            float dB = C21[boff + i] - C21n[boff + i];
            local += dA * dA + dB * dB;
        }
    } else {
        const float* xs; const float* ys; bool trans;
        switch (job) {
            case 0: xs = C12;  ys = C12;  trans = true;  break;
            case 1: xs = C21;  ys = C21;  trans = true;  break;
            case 2: xs = C12n; ys = C12n; trans = true;  break;
            case 3: xs = C21n; ys = C21n; trans = true;  break;
            case 4: xs = C12;  ys = C21;  trans = false; break;
            default: xs = C21; ys = C12;  trans = false; break;
        }
        for (int i = tid; i < KSP * KSP; i += 256) { X[i] = xs[boff + i]; Y[i] = ys[boff + i]; }
        __syncthreads();
        for (int idx = tid; idx < KSP * KSP; idx += 256) {
            int i = idx / KSP, j = idx % KSP;
            float s = 0.f;
            if (trans) {
                #pragma unroll 10
                for (int k = 0; k < KSP; ++k) s += X[i * KSP + k] * Y[j * KSP + k];
            } else {
                #pragma unroll 10
                for (int k = 0; k < KSP; ++k) s += X[i * KSP + k] * Y[k * KSP + j];
            }
            float d = s - ((i == j) ? 1.f : 0.f);
            local += d * d;
        }
    }

    #pragma unroll
    for (int off = 32; off; off >>= 1) local += __shfl_down(local, off, 64);
    __shared__ float ws4[4];
    int wave = tid >> 6, lane = tid & 63;
    if (lane == 0) ws4[wave] = local;
    __syncthreads();
    if (tid == 0) {
        float t = ws4[0] + ws4[1] + ws4[2] + ws4[3];
        int a = (job <= 3) ? 0 : ((job <= 5) ? 1 : 2);
        atomicAdd(&acc[a], t);
    }
}

// ---------------- K4: final combine ----------------
__global__ __launch_bounds__(256)
void final_kernel(const float* __restrict__ sims,
                  const float* __restrict__ acc,
                  float* __restrict__ out)
{
    int tid = threadIdx.x;
    float s = 0.f;
    for (int i = tid; i < 4 * NS; i += 256) s += sims[i];
    #pragma unroll
    for (int off = 32; off; off >>= 1) s += __shfl_down(s, off, 64);
    __shared__ float ws4[4];
    int wave = tid >> 6, lane = tid & 63;
    if (lane == 0) ws4[wave] = s;
    __syncthreads();
    if (tid == 0) {
        float dist_sum = ws4[0] + ws4[1] + ws4[2] + ws4[3];
        float dist_loss  = dist_sum * 0.5f;
        float ortho_loss = acc[0] * 0.25f;   // (sum of 4 frobs, each /B=2) * w/2
        float bij_loss   = acc[1] * 0.5f;    // /B
        float res_loss   = acc[2] * 0.5f;    // /B
        out[0] = dist_loss + ortho_loss + bij_loss + res_loss;
        out[1] = ortho_loss;
        out[2] = bij_loss;
        out[3] = res_loss;
        out[4] = dist_loss;
    }
}

static inline size_t align256(size_t x) { return (x + 255) & ~(size_t)255; }

extern "C" void kernel_launch(void* const* d_in, const int* in_sizes, int n_in,
                              void* d_out, int out_size, void* d_ws, size_t ws_size,
                              hipStream_t stream)
{
    const float* C12   = (const float*)d_in[0];
    const float* C21   = (const float*)d_in[1];
    const float* C12n  = (const float*)d_in[2];
    const float* C21n  = (const float*)d_in[3];
    const float* feat1 = (const float*)d_in[4];
    const float* feat2 = (const float*)d_in[5];
    // d_in[6], d_in[7]: evecs_trans1/2 — unused by the reference loss
    const float* dist1 = (const float*)d_in[8];
    const float* dist2 = (const float*)d_in[9];
    const int*   ridx1 = (const int*)d_in[10];
    const int*   ridx2 = (const int*)d_in[11];
    float* out = (float*)d_out;

    char* ws = (char*)d_ws;
    size_t off = 0;
    float* bb   = (float*)(ws + off); off += align256((size_t)4 * MPTS * sizeof(float));
    float* aa   = (float*)(ws + off); off += align256((size_t)4 * NS * sizeof(float));
    float* sims = (float*)(ws + off); off += align256((size_t)4 * NS * sizeof(float));
    float* acc  = (float*)(ws + off); off += align256(16 * sizeof(float));
    float* d2   = (float*)(ws + off);

    size_t avail = (ws_size > off) ? (ws_size - off) : 0;
    size_t chunk_sz = avail / ((size_t)MPTS * sizeof(float));
    int chunk = (int)((chunk_sz > NS) ? NS : chunk_sz);
    if (chunk < 1) chunk = 1;

    hipMemsetAsync(acc, 0, 16 * sizeof(float), stream);

    {
        int total = 4 * MPTS + 4 * NS;
        int blocks = (total + 255) / 256;
        norms_kernel<<<blocks, 256, 0, stream>>>(feat1, feat2, ridx1, ridx2, bb, aa);
    }

    for (int brb = 0; brb < 4; ++brb) {
        const float* feat = (brb < 2) ? feat1 : feat2;
        const int*   ridx = (brb < 2) ? ridx1 : ridx2;
        const float* dist = (brb < 2) ? dist1 : dist2;
        int b = brb & 1;
        const float* feat_b = feat + (size_t)b * MPTS * CDIM;
        const float* dist_b = dist + (size_t)b * MPTS * MPTS;

        for (int row0 = 0; row0 < NS; row0 += chunk) {
            int rows = NS - row0; if (rows > chunk) rows = chunk;
            dim3 g1((MPTS + BN - 1) / BN, (rows + BM - 1) / BM);
            d2_gemm_kernel<<<g1, 256, 0, stream>>>(feat_b, ridx,
                                                   aa + (size_t)brb * NS,
                                                   bb + (size_t)brb * MPTS,
                                                   d2, row0, rows);
            select_kernel<<<rows, 256, 0, stream>>>(d2, dist_b, ridx,
                                                    sims + (size_t)brb * NS + row0, row0);
        }
    }

    closs_kernel<<<14, 256, 0, stream>>>(C12, C21, C12n, C21n, acc);
    final_kernel<<<1, 256, 0, stream>>>(sims, acc, out);
}

// Round 6
// 940.286 us; speedup vs baseline: 1.1949x; 1.1949x over previous
//
#include <hip/hip_runtime.h>
#include <cstdint>
#include <cstddef>

#define K_NN   1000
#define NS     2000   // N_SAMPLE
#define MPTS   5000   // M
#define CDIM   128
#define KSP    50
#define EPSF   1e-8f

// float -> order-preserving uint key
__device__ __forceinline__ unsigned int f2key(float x) {
    unsigned int u = __float_as_uint(x);
    return (u & 0x80000000u) ? ~u : (u | 0x80000000u);
}
__device__ __forceinline__ float key2f(unsigned int k) {
    unsigned int b = (k & 0x80000000u) ? (k & 0x7fffffffu) : ~k;
    return __uint_as_float(b);
}

// ---------------- K0: squared norms ----------------
__global__ void norms_kernel(const float* __restrict__ feat1,
                             const float* __restrict__ feat2,
                             const int* __restrict__ ridx1,
                             const int* __restrict__ ridx2,
                             float* __restrict__ bb,
                             float* __restrict__ aa)
{
    int gid = blockIdx.x * blockDim.x + threadIdx.x;
    const int total_bb = 4 * MPTS;
    const int total_aa = 4 * NS;
    if (gid < total_bb) {
        int brb = gid / MPTS;
        int m   = gid % MPTS;
        const float* feat = (brb < 2) ? feat1 : feat2;
        int b = brb & 1;
        const float* row = feat + ((size_t)b * MPTS + m) * CDIM;
        float s = 0.f;
        #pragma unroll
        for (int c = 0; c < CDIM; c += 4) {
            float4 v = *reinterpret_cast<const float4*>(row + c);
            s += v.x*v.x + v.y*v.y + v.z*v.z + v.w*v.w;
        }
        bb[gid] = s;
    } else if (gid < total_bb + total_aa) {
        int t   = gid - total_bb;
        int brb = t / NS;
        int n   = t % NS;
        const float* feat = (brb < 2) ? feat1 : feat2;
        const int*  ridx  = (brb < 2) ? ridx1 : ridx2;
        int b = brb & 1;
        int m = ridx[n];
        const float* row = feat + ((size_t)b * MPTS + m) * CDIM;
        float s = 0.f;
        #pragma unroll
        for (int c = 0; c < CDIM; c += 4) {
            float4 v = *reinterpret_cast<const float4*>(row + c);
            s += v.x*v.x + v.y*v.y + v.z*v.z + v.w*v.w;
        }
        aa[t] = s;
    }
}

// ---------------- K1: d2 GEMM (writes orderable uint keys) ----------------
#define BM 128
#define BN 128
#define BK 32
__global__ __launch_bounds__(256)
void d2_gemm_kernel(const float* __restrict__ feat_b,
                    const int*   __restrict__ ridx,
                    const float* __restrict__ aa_bb,    // [NS]
                    const float* __restrict__ bb_bb,    // [MPTS]
                    unsigned int* __restrict__ d2k,     // [rows][MPTS] keys
                    int row0, int rows)
{
    __shared__ float As[BK][BM + 4];
    __shared__ float Bs[BK][BN + 4];

    const int tid = threadIdx.x;
    const int tx  = tid & 15;
    const int ty  = tid >> 4;
    const int m0  = blockIdx.x * BN;
    const int r0  = blockIdx.y * BM;

    float4 acc[2][4][2];
    #pragma unroll
    for (int ib = 0; ib < 2; ++ib)
      #pragma unroll
      for (int ii = 0; ii < 4; ++ii)
        #pragma unroll
        for (int jb = 0; jb < 2; ++jb)
            acc[ib][ii][jb] = make_float4(0.f, 0.f, 0.f, 0.f);

    const int lr = tid >> 3;           // 0..31
    const int lc = (tid & 7) << 2;     // 0,4,...,28
    int asrc[4]; int bsrc[4];
    #pragma unroll
    for (int p = 0; p < 4; ++p) {
        int r  = (p << 5) + lr;
        int rr = r0 + r;
        int n  = row0 + rr;
        asrc[p] = (rr < rows && n < NS) ? ridx[n] : 0;
        int m  = m0 + r;
        bsrc[p] = (m < MPTS) ? m : 0;
    }

    #define FMA4(ACC,S,Bv) { (ACC).x += (S)*(Bv).x; (ACC).y += (S)*(Bv).y; \
                             (ACC).z += (S)*(Bv).z; (ACC).w += (S)*(Bv).w; }

    for (int k0 = 0; k0 < CDIM; k0 += BK) {
        #pragma unroll
        for (int p = 0; p < 4; ++p) {
            int r = (p << 5) + lr;
            float4 v = *reinterpret_cast<const float4*>(feat_b + (size_t)asrc[p] * CDIM + k0 + lc);
            As[lc + 0][r] = v.x; As[lc + 1][r] = v.y; As[lc + 2][r] = v.z; As[lc + 3][r] = v.w;
            float4 w = *reinterpret_cast<const float4*>(feat_b + (size_t)bsrc[p] * CDIM + k0 + lc);
            Bs[lc + 0][r] = w.x; Bs[lc + 1][r] = w.y; Bs[lc + 2][r] = w.z; Bs[lc + 3][r] = w.w;
        }
        __syncthreads();
        #pragma unroll
        for (int k = 0; k < BK; ++k) {
            float4 a0 = *reinterpret_cast<const float4*>(&As[k][ty * 4]);
            float4 a1 = *reinterpret_cast<const float4*>(&As[k][64 + ty * 4]);
            float4 b0 = *reinterpret_cast<const float4*>(&Bs[k][tx * 4]);
            float4 b1 = *reinterpret_cast<const float4*>(&Bs[k][64 + tx * 4]);
            FMA4(acc[0][0][0], a0.x, b0); FMA4(acc[0][0][1], a0.x, b1);
            FMA4(acc[0][1][0], a0.y, b0); FMA4(acc[0][1][1], a0.y, b1);
            FMA4(acc[0][2][0], a0.z, b0); FMA4(acc[0][2][1], a0.z, b1);
            FMA4(acc[0][3][0], a0.w, b0); FMA4(acc[0][3][1], a0.w, b1);
            FMA4(acc[1][0][0], a1.x, b0); FMA4(acc[1][0][1], a1.x, b1);
            FMA4(acc[1][1][0], a1.y, b0); FMA4(acc[1][1][1], a1.y, b1);
            FMA4(acc[1][2][0], a1.z, b0); FMA4(acc[1][2][1], a1.z, b1);
            FMA4(acc[1][3][0], a1.w, b0); FMA4(acc[1][3][1], a1.w, b1);
        }
        __syncthreads();
    }

    // epilogue: key(aa + bb - 2*dot)
    #pragma unroll
    for (int ib = 0; ib < 2; ++ib) {
        #pragma unroll
        for (int ii = 0; ii < 4; ++ii) {
            int r = r0 + ib * 64 + ty * 4 + ii;
            if (r >= rows) continue;
            int n = row0 + r;
            float an = aa_bb[n];
            #pragma unroll
            for (int jb = 0; jb < 2; ++jb) {
                int m = m0 + jb * 64 + tx * 4;
                if (m >= MPTS) continue;
                float4 bv = *reinterpret_cast<const float4*>(bb_bb + m);
                float4 A = acc[ib][ii][jb];
                uint4 o;
                o.x = f2key(an + bv.x - 2.f * A.x);
                o.y = f2key(an + bv.y - 2.f * A.y);
                o.z = f2key(an + bv.z - 2.f * A.z);
                o.w = f2key(an + bv.w - 2.f * A.w);
                *reinterpret_cast<uint4*>(d2k + (size_t)r * MPTS + m) = o;
            }
        }
    }
}

// ---------------- block-wide exclusive scan (256 threads, 4 waves) ----------
__device__ __forceinline__ unsigned int block_excl_scan(unsigned int v,
                                                        volatile unsigned int* wtot,
                                                        int tid)
{
    int lane = tid & 63, wv = tid >> 6;
    unsigned int x = v;
    #pragma unroll
    for (int off = 1; off < 64; off <<= 1) {
        unsigned int y = (unsigned int)__shfl_up((int)x, off, 64);
        if (lane >= off) x += y;
    }
    if (lane == 63) wtot[wv] = x;
    __syncthreads();
    unsigned int woff = 0;
    #pragma unroll
    for (int w = 0; w < 4; ++w) woff += (w < wv) ? wtot[w] : 0u;
    return woff + x - v;
}

// ---------------- K2a: radix-select + deterministic compaction --------------
__global__ __launch_bounds__(256)
void select_compact_kernel(unsigned int* __restrict__ d2k,   // keys in, compact out (in-place)
                           int row0)
{
    __shared__ unsigned int keys[MPTS];
    __shared__ unsigned int whist[4][256];
    __shared__ unsigned int wtot[4];
    __shared__ unsigned int bcp, bck;
    __shared__ unsigned short sidx[K_NN];
    __shared__ float sval[K_NN];

    const int tid = threadIdx.x;
    const int r   = blockIdx.x;
    unsigned int* rowp = d2k + (size_t)r * MPTS;

    // load keys
    const uint4* rp4 = reinterpret_cast<const uint4*>(rowp);
    for (int i4 = tid; i4 < MPTS / 4; i4 += 256) {
        uint4 v = rp4[i4];
        keys[i4 * 4 + 0] = v.x; keys[i4 * 4 + 1] = v.y;
        keys[i4 * 4 + 2] = v.z; keys[i4 * 4 + 3] = v.w;
    }
    __syncthreads();

    // MSB-first radix select, parallel bucket pick
    unsigned int prefix = 0;
    unsigned int krem = K_NN;
    const int wv = tid >> 6;
    #pragma unroll
    for (int pass = 0; pass < 4; ++pass) {
        const int shift = 24 - 8 * pass;
        #pragma unroll
        for (int w = 0; w < 4; ++w) whist[w][tid] = 0;
        __syncthreads();
        for (int i = tid; i < MPTS; i += 256) {
            unsigned int k = keys[i];
            bool ok = (pass == 0) || ((k >> (32 - 8 * (pass == 0 ? 1 : pass))) == prefix);
            if (ok) atomicAdd(&whist[wv][(k >> shift) & 255u], 1u);
        }
        __syncthreads();
        unsigned int h = whist[0][tid] + whist[1][tid] + whist[2][tid] + whist[3][tid];
        unsigned int excl = block_excl_scan(h, wtot, tid);
        if (krem > excl && krem <= excl + h) {
            bcp = (prefix << 8) | (unsigned int)tid;
            bck = krem - excl;
        }
        __syncthreads();
        prefix = bcp;
        krem   = bck;
        __syncthreads();
    }
    const unsigned int T = prefix;
    const unsigned int need_eq = krem;

    // deterministic stable compaction (index order)
    const int start = tid * 20;
    const int end_  = (start + 20 < MPTS) ? start + 20 : MPTS;
    unsigned int cl = 0, ce = 0;
    for (int i = start; i < end_; ++i) {
        unsigned int k = keys[i];
        cl += (k < T) ? 1u : 0u;
        ce += (k == T) ? 1u : 0u;
    }
    unsigned int pex = block_excl_scan((cl << 16) | ce, wtot, tid);
    unsigned int lt_run = pex >> 16;
    unsigned int eq_run = pex & 0xffffu;
    for (int i = start; i < end_; ++i) {
        unsigned int k = keys[i];
        if (k < T) {
            unsigned int taken_eq = (eq_run < need_eq) ? eq_run : need_eq;
            unsigned int pos = lt_run + taken_eq;
            sidx[pos] = (unsigned short)i;
            sval[pos] = __builtin_sqrtf(fmaxf(key2f(k), 1e-12f));
            ++lt_run;
        } else if (k == T) {
            if (eq_run < need_eq) {
                unsigned int pos = lt_run + eq_run;
                sidx[pos] = (unsigned short)i;
                sval[pos] = __builtin_sqrtf(fmaxf(key2f(k), 1e-12f));
            }
            ++eq_run;
        }
    }
    __syncthreads();

    // flush compact lists back into the row (idx at [0:1000), val at [1000:2000))
    for (int j = tid; j < K_NN; j += 256) {
        rowp[j]        = (unsigned int)sidx[j];
        rowp[K_NN + j] = __float_as_uint(sval[j]);
    }
}

// ---------------- K2b: pure gather + cosine reduction ----------------------
__global__ __launch_bounds__(256)
void gather_reduce_kernel(const unsigned int* __restrict__ d2k,
                          const float* __restrict__ dist_b,
                          const int*   __restrict__ ridx,
                          float* __restrict__ sims_out,
                          int row0)
{
    __shared__ float wsum[3][4];
    const int tid = threadIdx.x;
    const int r   = blockIdx.x;
    const unsigned int* rowp = d2k + (size_t)r * MPTS;
    const int col = ridx[row0 + r];

    const int j0 = tid, j1 = tid + 256, j2 = tid + 512, j3 = tid + 768;
    const bool v3 = (j3 < K_NN);

    unsigned int i0 = rowp[j0];
    unsigned int i1 = rowp[j1];
    unsigned int i2 = rowp[j2];
    unsigned int i3 = v3 ? rowp[j3] : 0u;
    float q0 = __uint_as_float(rowp[K_NN + j0]);
    float q1 = __uint_as_float(rowp[K_NN + j1]);
    float q2 = __uint_as_float(rowp[K_NN + j2]);
    float q3 = v3 ? __uint_as_float(rowp[K_NN + j3]) : 0.f;

    float f0 = dist_b[(size_t)i0 * MPTS + col];
    float f1 = dist_b[(size_t)i1 * MPTS + col];
    float f2 = dist_b[(size_t)i2 * MPTS + col];
    float f3 = v3 ? dist_b[(size_t)i3 * MPTS + col] : 0.f;

    float num = q0 * f0 + q1 * f1 + q2 * f2 + q3 * f3;
    float s1  = q0 * q0 + q1 * q1 + q2 * q2 + q3 * q3;
    float s2  = f0 * f0 + f1 * f1 + f2 * f2 + f3 * f3;

    #pragma unroll
    for (int off = 32; off; off >>= 1) {
        num += __shfl_down(num, off, 64);
        s1  += __shfl_down(s1,  off, 64);
        s2  += __shfl_down(s2,  off, 64);
    }
    int wave = tid >> 6, lane = tid & 63;
    if (lane == 0) { wsum[0][wave] = num; wsum[1][wave] = s1; wsum[2][wave] = s2; }
    __syncthreads();
    if (tid == 0) {
        float N = wsum[0][0] + wsum[0][1] + wsum[0][2] + wsum[0][3];
        float A = wsum[1][0] + wsum[1][1] + wsum[1][2] + wsum[1][3];
        float B = wsum[2][0] + wsum[2][1] + wsum[2][2] + wsum[2][3];
        float den = fmaxf(__builtin_sqrtf(A), EPSF) * fmaxf(__builtin_sqrtf(B), EPSF);
        sims_out[r] = 1.f - fabsf(N / den);
    }
}

// ---------------- K3: small C-matrix losses ----------------
__global__ __launch_bounds__(256)
void closs_kernel(const float* __restrict__ C12,  const float* __restrict__ C21,
                  const float* __restrict__ C12n, const float* __restrict__ C21n,
                  float* __restrict__ acc)
{
    int job = blockIdx.x >> 1;
    int b   = blockIdx.x & 1;
    int tid = threadIdx.x;
    size_t boff = (size_t)b * KSP * KSP;
    __shared__ float X[KSP * KSP];
    __shared__ float Y[KSP * KSP];
    float local = 0.f;

    if (job == 6) {
        for (int i = tid; i < KSP * KSP; i += 256) {
            float dA = C12[boff + i] - C12n[boff + i];
            float dB = C21[boff + i] - C21n[boff + i];
            local += dA * dA + dB * dB;
        }
    } else {
        const float* xs; const float* ys; bool trans;
        switch (job) {
            case 0: xs = C12;  ys = C12;  trans = true;  break;
            case 1: xs = C21;  ys = C21;  trans = true;  break;
            case 2: xs = C12n; ys = C12n; trans = true;  break;
            case 3: xs = C21n; ys = C21n; trans = true;  break;
            case 4: xs = C12;  ys = C21;  trans = false; break;
            default: xs = C21; ys = C12;  trans = false; break;
        }
        for (int i = tid; i < KSP * KSP; i += 256) { X[i] = xs[boff + i]; Y[i] = ys[boff + i]; }
        __syncthreads();
        for (int idx = tid; idx < KSP * KSP; idx += 256) {
            int i = idx / KSP, j = idx % KSP;
            float s = 0.f;
            if (trans) {
                #pragma unroll 10
                for (int k = 0; k < KSP; ++k) s += X[i * KSP + k] * Y[j * KSP + k];
            } else {
                #pragma unroll 10
                for (int k = 0; k < KSP; ++k) s += X[i * KSP + k] * Y[k * KSP + j];
            }
            float d = s - ((i == j) ? 1.f : 0.f);
            local += d * d;
        }
    }

    #pragma unroll
    for (int off = 32; off; off >>= 1) local += __shfl_down(local, off, 64);
    __shared__ float ws4[4];
    int wave = tid >> 6, lane = tid & 63;
    if (lane == 0) ws4[wave] = local;
    __syncthreads();
    if (tid == 0) {
        float t = ws4[0] + ws4[1] + ws4[2] + ws4[3];
        int a = (job <= 3) ? 0 : ((job <= 5) ? 1 : 2);
        atomicAdd(&acc[a], t);
    }
}

// ---------------- K4: final combine ----------------
__global__ __launch_bounds__(256)
void final_kernel(const float* __restrict__ sims,
                  const float* __restrict__ acc,
                  float* __restrict__ out)
{
    int tid = threadIdx.x;
    float s = 0.f;
    for (int i = tid; i < 4 * NS; i += 256) s += sims[i];
    #pragma unroll
    for (int off = 32; off; off >>= 1) s += __shfl_down(s, off, 64);
    __shared__ float ws4[4];
    int wave = tid >> 6, lane = tid & 63;
    if (lane == 0) ws4[wave] = s;
    __syncthreads();
    if (tid == 0) {
        float dist_sum = ws4[0] + ws4[1] + ws4[2] + ws4[3];
        float dist_loss  = dist_sum * 0.5f;
        float ortho_loss = acc[0] * 0.25f;
        float bij_loss   = acc[1] * 0.5f;
        float res_loss   = acc[2] * 0.5f;
        out[0] = dist_loss + ortho_loss + bij_loss + res_loss;
        out[1] = ortho_loss;
        out[2] = bij_loss;
        out[3] = res_loss;
        out[4] = dist_loss;
    }
}

static inline size_t align256(size_t x) { return (x + 255) & ~(size_t)255; }

extern "C" void kernel_launch(void* const* d_in, const int* in_sizes, int n_in,
                              void* d_out, int out_size, void* d_ws, size_t ws_size,
                              hipStream_t stream)
{
    const float* C12   = (const float*)d_in[0];
    const float* C21   = (const float*)d_in[1];
    const float* C12n  = (const float*)d_in[2];
    const float* C21n  = (const float*)d_in[3];
    const float* feat1 = (const float*)d_in[4];
    const float* feat2 = (const float*)d_in[5];
    const float* dist1 = (const float*)d_in[8];
    const float* dist2 = (const float*)d_in[9];
    const int*   ridx1 = (const int*)d_in[10];
    const int*   ridx2 = (const int*)d_in[11];
    float* out = (float*)d_out;

    char* ws = (char*)d_ws;
    size_t off = 0;
    float* bb   = (float*)(ws + off); off += align256((size_t)4 * MPTS * sizeof(float));
    float* aa   = (float*)(ws + off); off += align256((size_t)4 * NS * sizeof(float));
    float* sims = (float*)(ws + off); off += align256((size_t)4 * NS * sizeof(float));
    float* acc  = (float*)(ws + off); off += align256(16 * sizeof(float));
    unsigned int* d2k = (unsigned int*)(ws + off);

    size_t avail = (ws_size > off) ? (ws_size - off) : 0;
    size_t chunk_sz = avail / ((size_t)MPTS * sizeof(unsigned int));
    int chunk = (int)((chunk_sz > NS) ? NS : chunk_sz);
    if (chunk < 1) chunk = 1;

    hipMemsetAsync(acc, 0, 16 * sizeof(float), stream);

    {
        int total = 4 * MPTS + 4 * NS;
        int blocks = (total + 255) / 256;
        norms_kernel<<<blocks, 256, 0, stream>>>(feat1, feat2, ridx1, ridx2, bb, aa);
    }

    for (int brb = 0; brb < 4; ++brb) {
        const float* feat = (brb < 2) ? feat1 : feat2;
        const int*   ridx = (brb < 2) ? ridx1 : ridx2;
        const float* dist = (brb < 2) ? dist1 : dist2;
        int b = brb & 1;
        const float* feat_b = feat + (size_t)b * MPTS * CDIM;
        const float* dist_b = dist + (size_t)b * MPTS * MPTS;

        for (int row0 = 0; row0 < NS; row0 += chunk) {
            int rows = NS - row0; if (rows > chunk) rows = chunk;
            dim3 g1((MPTS + BN - 1) / BN, (rows + BM - 1) / BM);
            d2_gemm_kernel<<<g1, 256, 0, stream>>>(feat_b, ridx,
                                                   aa + (size_t)brb * NS,
                                                   bb + (size_t)brb * MPTS,
                                                   d2k, row0, rows);
            select_compact_kernel<<<rows, 256, 0, stream>>>(d2k, row0);
            gather_reduce_kernel<<<rows, 256, 0, stream>>>(d2k, dist_b, ridx,
                                                           sims + (size_t)brb * NS + row0, row0);
        }
    }

    closs_kernel<<<14, 256, 0, stream>>>(C12, C21, C12n, C21n, acc);
    final_kernel<<<1, 256, 0, stream>>>(sims, acc, out);
}

// Round 7
// 826.261 us; speedup vs baseline: 1.3598x; 1.1380x over previous
//
#include <hip/hip_runtime.h>
#include <cstdint>
#include <cstddef>

#define K_NN   1000
#define NS     2000   // N_SAMPLE
#define MPTS   5000   // M
#define CDIM   128
#define KSP    50
#define EPSF   1e-8f

// float -> order-preserving uint key
__device__ __forceinline__ unsigned int f2key(float x) {
    unsigned int u = __float_as_uint(x);
    return (u & 0x80000000u) ? ~u : (u | 0x80000000u);
}
__device__ __forceinline__ float key2f(unsigned int k) {
    unsigned int b = (k & 0x80000000u) ? (k & 0x7fffffffu) : ~k;
    return __uint_as_float(b);
}

// ---------------- K0: squared norms (bb only; aa[n] == bb[ridx[n]]) --------
__global__ void norms_kernel(const float* __restrict__ feat1,
                             const float* __restrict__ feat2,
                             float* __restrict__ bb)
{
    int gid = blockIdx.x * blockDim.x + threadIdx.x;
    if (gid >= 4 * MPTS) return;
    int brb = gid / MPTS;
    int m   = gid % MPTS;
    const float* feat = (brb < 2) ? feat1 : feat2;
    int b = brb & 1;
    const float* row = feat + ((size_t)b * MPTS + m) * CDIM;
    float s = 0.f;
    #pragma unroll
    for (int c = 0; c < CDIM; c += 4) {
        float4 v = *reinterpret_cast<const float4*>(row + c);
        s += v.x*v.x + v.y*v.y + v.z*v.z + v.w*v.w;
    }
    bb[gid] = s;
}

// ---------------- K1: d2 GEMM (all branch-batches via blockIdx.z) ----------
#define BM 128
#define BN 128
#define BK 32
__global__ __launch_bounds__(256)
void d2_gemm_kernel(const float* __restrict__ feat1,
                    const float* __restrict__ feat2,
                    const int*   __restrict__ ridx1,
                    const int*   __restrict__ ridx2,
                    const float* __restrict__ bb,       // [4][MPTS]
                    unsigned int* __restrict__ d2k,
                    size_t brb_stride,                   // elements per brb slab
                    int brb_base, int row0, int rows)
{
    const int brb = brb_base + blockIdx.z;
    const float* feat_b = ((brb < 2) ? feat1 : feat2) + (size_t)(brb & 1) * MPTS * CDIM;
    const int*   ridx   = (brb < 2) ? ridx1 : ridx2;
    const float* bb_bb  = bb + (size_t)brb * MPTS;
    unsigned int* outp  = d2k + (size_t)blockIdx.z * brb_stride;

    __shared__ float As[BK][BM + 4];
    __shared__ float Bs[BK][BN + 4];

    const int tid = threadIdx.x;
    const int tx  = tid & 15;
    const int ty  = tid >> 4;
    const int m0  = blockIdx.x * BN;
    const int r0  = blockIdx.y * BM;

    float4 acc[2][4][2];
    #pragma unroll
    for (int ib = 0; ib < 2; ++ib)
      #pragma unroll
      for (int ii = 0; ii < 4; ++ii)
        #pragma unroll
        for (int jb = 0; jb < 2; ++jb)
            acc[ib][ii][jb] = make_float4(0.f, 0.f, 0.f, 0.f);

    const int lr = tid >> 3;           // 0..31
    const int lc = (tid & 7) << 2;     // 0,4,...,28
    int asrc[4]; int bsrc[4];
    #pragma unroll
    for (int p = 0; p < 4; ++p) {
        int r  = (p << 5) + lr;
        int rr = r0 + r;
        asrc[p] = (rr < rows) ? ridx[row0 + rr] : 0;
        int m  = m0 + r;
        bsrc[p] = (m < MPTS) ? m : 0;
    }

    #define FMA4(ACC,S,Bv) { (ACC).x += (S)*(Bv).x; (ACC).y += (S)*(Bv).y; \
                             (ACC).z += (S)*(Bv).z; (ACC).w += (S)*(Bv).w; }

    for (int k0 = 0; k0 < CDIM; k0 += BK) {
        #pragma unroll
        for (int p = 0; p < 4; ++p) {
            int r = (p << 5) + lr;
            float4 v = *reinterpret_cast<const float4*>(feat_b + (size_t)asrc[p] * CDIM + k0 + lc);
            As[lc + 0][r] = v.x; As[lc + 1][r] = v.y; As[lc + 2][r] = v.z; As[lc + 3][r] = v.w;
            float4 w = *reinterpret_cast<const float4*>(feat_b + (size_t)bsrc[p] * CDIM + k0 + lc);
            Bs[lc + 0][r] = w.x; Bs[lc + 1][r] = w.y; Bs[lc + 2][r] = w.z; Bs[lc + 3][r] = w.w;
        }
        __syncthreads();
        #pragma unroll
        for (int k = 0; k < BK; ++k) {
            float4 a0 = *reinterpret_cast<const float4*>(&As[k][ty * 4]);
            float4 a1 = *reinterpret_cast<const float4*>(&As[k][64 + ty * 4]);
            float4 b0 = *reinterpret_cast<const float4*>(&Bs[k][tx * 4]);
            float4 b1 = *reinterpret_cast<const float4*>(&Bs[k][64 + tx * 4]);
            FMA4(acc[0][0][0], a0.x, b0); FMA4(acc[0][0][1], a0.x, b1);
            FMA4(acc[0][1][0], a0.y, b0); FMA4(acc[0][1][1], a0.y, b1);
            FMA4(acc[0][2][0], a0.z, b0); FMA4(acc[0][2][1], a0.z, b1);
            FMA4(acc[0][3][0], a0.w, b0); FMA4(acc[0][3][1], a0.w, b1);
            FMA4(acc[1][0][0], a1.x, b0); FMA4(acc[1][0][1], a1.x, b1);
            FMA4(acc[1][1][0], a1.y, b0); FMA4(acc[1][1][1], a1.y, b1);
            FMA4(acc[1][2][0], a1.z, b0); FMA4(acc[1][2][1], a1.z, b1);
            FMA4(acc[1][3][0], a1.w, b0); FMA4(acc[1][3][1], a1.w, b1);
        }
        __syncthreads();
    }

    // epilogue: key(aa + bb - 2*dot), aa gathered as bb[ridx[n]]
    #pragma unroll
    for (int ib = 0; ib < 2; ++ib) {
        #pragma unroll
        for (int ii = 0; ii < 4; ++ii) {
            int r = r0 + ib * 64 + ty * 4 + ii;
            if (r >= rows) continue;
            int n = row0 + r;
            float an = bb_bb[ridx[n]];
            #pragma unroll
            for (int jb = 0; jb < 2; ++jb) {
                int m = m0 + jb * 64 + tx * 4;
                if (m >= MPTS) continue;
                float4 bv = *reinterpret_cast<const float4*>(bb_bb + m);
                float4 A = acc[ib][ii][jb];
                uint4 o;
                o.x = f2key(an + bv.x - 2.f * A.x);
                o.y = f2key(an + bv.y - 2.f * A.y);
                o.z = f2key(an + bv.z - 2.f * A.z);
                o.w = f2key(an + bv.w - 2.f * A.w);
                *reinterpret_cast<uint4*>(outp + (size_t)r * MPTS + m) = o;
            }
        }
    }
}

// ---------------- block-wide exclusive scan (256 threads, 4 waves) ----------
__device__ __forceinline__ unsigned int block_excl_scan(unsigned int v,
                                                        volatile unsigned int* wtot,
                                                        int tid)
{
    int lane = tid & 63, wv = tid >> 6;
    unsigned int x = v;
    #pragma unroll
    for (int off = 1; off < 64; off <<= 1) {
        unsigned int y = (unsigned int)__shfl_up((int)x, off, 64);
        if (lane >= off) x += y;
    }
    if (lane == 63) wtot[wv] = x;
    __syncthreads();
    unsigned int woff = 0;
    #pragma unroll
    for (int w = 0; w < 4; ++w) woff += (w < wv) ? wtot[w] : 0u;
    return woff + x - v;
}

// -------- K2: fused radix-select + compaction + gather + cosine ------------
__global__ __launch_bounds__(256)
void select_gather_kernel(const unsigned int* __restrict__ d2k,
                          const float* __restrict__ dist1,
                          const float* __restrict__ dist2,
                          const int*   __restrict__ ridx1,
                          const int*   __restrict__ ridx2,
                          float* __restrict__ sims,      // [4][NS]
                          size_t brb_stride,
                          int brb_base, int row0)
{
    __shared__ unsigned int keys[MPTS];
    __shared__ unsigned int whist[4][256];
    __shared__ unsigned int wtot[4];
    __shared__ unsigned int bcp, bck;
    __shared__ unsigned short sidx[K_NN];
    __shared__ float sval[K_NN];
    __shared__ float wsum[3][4];

    const int tid = threadIdx.x;
    const int r   = blockIdx.x;                 // chunk-local row
    const int brb = brb_base + blockIdx.y;
    const unsigned int* rowp = d2k + (size_t)blockIdx.y * brb_stride + (size_t)r * MPTS;
    const float* dist_b = ((brb < 2) ? dist1 : dist2) + (size_t)(brb & 1) * MPTS * MPTS;
    const int*   ridx   = (brb < 2) ? ridx1 : ridx2;
    const int n   = row0 + r;
    const int col = ridx[n];

    // load keys
    const uint4* rp4 = reinterpret_cast<const uint4*>(rowp);
    for (int i4 = tid; i4 < MPTS / 4; i4 += 256) {
        uint4 v = rp4[i4];
        keys[i4 * 4 + 0] = v.x; keys[i4 * 4 + 1] = v.y;
        keys[i4 * 4 + 2] = v.z; keys[i4 * 4 + 3] = v.w;
    }
    __syncthreads();

    // MSB-first radix select, parallel bucket pick
    unsigned int prefix = 0;
    unsigned int krem = K_NN;
    const int wv = tid >> 6;
    #pragma unroll
    for (int pass = 0; pass < 4; ++pass) {
        const int shift = 24 - 8 * pass;
        #pragma unroll
        for (int w = 0; w < 4; ++w) whist[w][tid] = 0;
        __syncthreads();
        for (int i = tid; i < MPTS; i += 256) {
            unsigned int k = keys[i];
            bool ok = (pass == 0) || ((k >> (shift + 8)) == prefix);
            if (ok) atomicAdd(&whist[wv][(k >> shift) & 255u], 1u);
        }
        __syncthreads();
        unsigned int h = whist[0][tid] + whist[1][tid] + whist[2][tid] + whist[3][tid];
        unsigned int excl = block_excl_scan(h, wtot, tid);
        if (krem > excl && krem <= excl + h) {
            bcp = (prefix << 8) | (unsigned int)tid;
            bck = krem - excl;
        }
        __syncthreads();
        prefix = bcp;
        krem   = bck;
        __syncthreads();
    }
    const unsigned int T = prefix;
    const unsigned int need_eq = krem;

    // deterministic stable compaction (index order) into sidx/sval
    const int start = tid * 20;
    const int end_  = (start + 20 < MPTS) ? start + 20 : MPTS;
    unsigned int cl = 0, ce = 0;
    for (int i = start; i < end_; ++i) {
        unsigned int k = keys[i];
        cl += (k < T) ? 1u : 0u;
        ce += (k == T) ? 1u : 0u;
    }
    unsigned int pex = block_excl_scan((cl << 16) | ce, wtot, tid);
    unsigned int lt_run = pex >> 16;
    unsigned int eq_run = pex & 0xffffu;
    for (int i = start; i < end_; ++i) {
        unsigned int k = keys[i];
        if (k < T) {
            unsigned int taken_eq = (eq_run < need_eq) ? eq_run : need_eq;
            unsigned int pos = lt_run + taken_eq;
            sidx[pos] = (unsigned short)i;
            sval[pos] = __builtin_sqrtf(fmaxf(key2f(k), 1e-12f));
            ++lt_run;
        } else if (k == T) {
            if (eq_run < need_eq) {
                unsigned int pos = lt_run + eq_run;
                sidx[pos] = (unsigned short)i;
                sval[pos] = __builtin_sqrtf(fmaxf(key2f(k), 1e-12f));
            }
            ++eq_run;
        }
    }
    __syncthreads();

    // gather + cosine reduction straight from LDS lists
    const int j0 = tid, j1 = tid + 256, j2 = tid + 512, j3 = tid + 768;
    const bool v3 = (j3 < K_NN);

    unsigned int i0 = sidx[j0];
    unsigned int i1 = sidx[j1];
    unsigned int i2 = sidx[j2];
    unsigned int i3 = v3 ? sidx[j3] : 0u;
    float q0 = sval[j0];
    float q1 = sval[j1];
    float q2 = sval[j2];
    float q3 = v3 ? sval[j3] : 0.f;

    float f0 = dist_b[(size_t)i0 * MPTS + col];
    float f1 = dist_b[(size_t)i1 * MPTS + col];
    float f2 = dist_b[(size_t)i2 * MPTS + col];
    float f3 = v3 ? dist_b[(size_t)i3 * MPTS + col] : 0.f;

    float num = q0 * f0 + q1 * f1 + q2 * f2 + q3 * f3;
    float s1  = q0 * q0 + q1 * q1 + q2 * q2 + q3 * q3;
    float s2  = f0 * f0 + f1 * f1 + f2 * f2 + f3 * f3;

    #pragma unroll
    for (int off = 32; off; off >>= 1) {
        num += __shfl_down(num, off, 64);
        s1  += __shfl_down(s1,  off, 64);
        s2  += __shfl_down(s2,  off, 64);
    }
    int lane = tid & 63;
    if (lane == 0) { wsum[0][wv] = num; wsum[1][wv] = s1; wsum[2][wv] = s2; }
    __syncthreads();
    if (tid == 0) {
        float N = wsum[0][0] + wsum[0][1] + wsum[0][2] + wsum[0][3];
        float A = wsum[1][0] + wsum[1][1] + wsum[1][2] + wsum[1][3];
        float B = wsum[2][0] + wsum[2][1] + wsum[2][2] + wsum[2][3];
        float den = fmaxf(__builtin_sqrtf(A), EPSF) * fmaxf(__builtin_sqrtf(B), EPSF);
        sims[(size_t)brb * NS + n] = 1.f - fabsf(N / den);
    }
}

// ---------------- K3: small C-matrix losses ----------------
__global__ __launch_bounds__(256)
void closs_kernel(const float* __restrict__ C12,  const float* __restrict__ C21,
                  const float* __restrict__ C12n, const float* __restrict__ C21n,
                  float* __restrict__ acc)
{
    int job = blockIdx.x >> 1;
    int b   = blockIdx.x & 1;
    int tid = threadIdx.x;
    size_t boff = (size_t)b * KSP * KSP;
    __shared__ float X[KSP * KSP];
    __shared__ float Y[KSP * KSP];
    float local = 0.f;

    if (job == 6) {
        for (int i = tid; i < KSP * KSP; i += 256) {
            float dA = C12[boff + i] - C12n[boff + i];
            float dB = C21[boff + i] - C21n[boff + i];
            local += dA * dA + dB * dB;
        }
    } else {
        const float* xs; const float* ys; bool trans;
        switch (job) {
            case 0: xs = C12;  ys = C12;  trans = true;  break;
            case 1: xs = C21;  ys = C21;  trans = true;  break;
            case 2: xs = C12n; ys = C12n; trans = true;  break;
            case 3: xs = C21n; ys = C21n; trans = true;  break;
            case 4: xs = C12;  ys = C21;  trans = false; break;
            default: xs = C21; ys = C12;  trans = false; break;
        }
        for (int i = tid; i < KSP * KSP; i += 256) { X[i] = xs[boff + i]; Y[i] = ys[boff + i]; }
        __syncthreads();
        for (int idx = tid; idx < KSP * KSP; idx += 256) {
            int i = idx / KSP, j = idx % KSP;
            float s = 0.f;
            if (trans) {
                #pragma unroll 10
                for (int k = 0; k < KSP; ++k) s += X[i * KSP + k] * Y[j * KSP + k];
            } else {
                #pragma unroll 10
                for (int k = 0; k < KSP; ++k) s += X[i * KSP + k] * Y[k * KSP + j];
            }
            float d = s - ((i == j) ? 1.f : 0.f);
            local += d * d;
        }
    }

    #pragma unroll
    for (int off = 32; off; off >>= 1) local += __shfl_down(local, off, 64);
    __shared__ float ws4[4];
    int wave = tid >> 6, lane = tid & 63;
    if (lane == 0) ws4[wave] = local;
    __syncthreads();
    if (tid == 0) {
        float t = ws4[0] + ws4[1] + ws4[2] + ws4[3];
        int a = (job <= 3) ? 0 : ((job <= 5) ? 1 : 2);
        atomicAdd(&acc[a], t);
    }
}

// ---------------- K4: final combine ----------------
__global__ __launch_bounds__(256)
void final_kernel(const float* __restrict__ sims,
                  const float* __restrict__ acc,
                  float* __restrict__ out)
{
    int tid = threadIdx.x;
    float s = 0.f;
    for (int i = tid; i < 4 * NS; i += 256) s += sims[i];
    #pragma unroll
    for (int off = 32; off; off >>= 1) s += __shfl_down(s, off, 64);
    __shared__ float ws4[4];
    int wave = tid >> 6, lane = tid & 63;
    if (lane == 0) ws4[wave] = s;
    __syncthreads();
    if (tid == 0) {
        float dist_sum = ws4[0] + ws4[1] + ws4[2] + ws4[3];
        float dist_loss  = dist_sum * 0.5f;
        float ortho_loss = acc[0] * 0.25f;
        float bij_loss   = acc[1] * 0.5f;
        float res_loss   = acc[2] * 0.5f;
        out[0] = dist_loss + ortho_loss + bij_loss + res_loss;
        out[1] = ortho_loss;
        out[2] = bij_loss;
        out[3] = res_loss;
        out[4] = dist_loss;
    }
}

static inline size_t align256(size_t x) { return (x + 255) & ~(size_t)255; }

extern "C" void kernel_launch(void* const* d_in, const int* in_sizes, int n_in,
                              void* d_out, int out_size, void* d_ws, size_t ws_size,
                              hipStream_t stream)
{
    const float* C12   = (const float*)d_in[0];
    const float* C21   = (const float*)d_in[1];
    const float* C12n  = (const float*)d_in[2];
    const float* C21n  = (const float*)d_in[3];
    const float* feat1 = (const float*)d_in[4];
    const float* feat2 = (const float*)d_in[5];
    const float* dist1 = (const float*)d_in[8];
    const float* dist2 = (const float*)d_in[9];
    const int*   ridx1 = (const int*)d_in[10];
    const int*   ridx2 = (const int*)d_in[11];
    float* out = (float*)d_out;

    char* ws = (char*)d_ws;
    size_t off = 0;
    float* bb   = (float*)(ws + off); off += align256((size_t)4 * MPTS * sizeof(float));
    float* sims = (float*)(ws + off); off += align256((size_t)4 * NS * sizeof(float));
    float* acc  = (float*)(ws + off); off += align256(16 * sizeof(float));
    unsigned int* d2k = (unsigned int*)(ws + off);

    const size_t slab = (size_t)NS * MPTS;            // elements per brb
    size_t avail_elems = (ws_size > off) ? (ws_size - off) / sizeof(unsigned int) : 0;

    hipMemsetAsync(acc, 0, 16 * sizeof(float), stream);
    norms_kernel<<<(4 * MPTS + 255) / 256, 256, 0, stream>>>(feat1, feat2, bb);

    if (avail_elems >= 4 * slab) {
        // ---- mega path: one GEMM launch + one fused select/gather launch ----
        dim3 gg((MPTS + BN - 1) / BN, (NS + BM - 1) / BM, 4);
        d2_gemm_kernel<<<gg, 256, 0, stream>>>(feat1, feat2, ridx1, ridx2, bb,
                                               d2k, slab, 0, 0, NS);
        dim3 gs(NS, 4);
        select_gather_kernel<<<gs, 256, 0, stream>>>(d2k, dist1, dist2, ridx1, ridx2,
                                                     sims, slab, 0, 0);
    } else {
        // ---- fallback: chunk rows, loop branch-batches ----
        size_t chunk_sz = avail_elems / MPTS;
        int chunk = (int)((chunk_sz > NS) ? NS : chunk_sz);
        if (chunk < 1) chunk = 1;
        for (int brb = 0; brb < 4; ++brb) {
            for (int row0 = 0; row0 < NS; row0 += chunk) {
                int rows = NS - row0; if (rows > chunk) rows = chunk;
                dim3 g1((MPTS + BN - 1) / BN, (rows + BM - 1) / BM, 1);
                d2_gemm_kernel<<<g1, 256, 0, stream>>>(feat1, feat2, ridx1, ridx2, bb,
                                                       d2k, 0, brb, row0, rows);
                dim3 g2(rows, 1);
                select_gather_kernel<<<g2, 256, 0, stream>>>(d2k, dist1, dist2, ridx1, ridx2,
                                                             sims, 0, brb, row0);
            }
        }
    }

    closs_kernel<<<14, 256, 0, stream>>>(C12, C21, C12n, C21n, acc);
    final_kernel<<<1, 256, 0, stream>>>(sims, acc, out);
}